// Round 3
// baseline (12104.917 us; speedup 1.0000x reference)
//
#include <hip/hip_runtime.h>

typedef unsigned short u16;
typedef unsigned int   u32;
typedef unsigned long long u64;
typedef short s16x4 __attribute__((ext_vector_type(4)));
typedef short s16x8 __attribute__((ext_vector_type(8)));
typedef float f32x4 __attribute__((ext_vector_type(4)));
typedef u32   u32x4 __attribute__((ext_vector_type(4)));

#define GK 1024

__device__ inline u16 f2bf(float f) {
    u32 u = __builtin_bit_cast(u32, f);
    u += 0x7FFFu + ((u >> 16) & 1u);
    return (u16)(u >> 16);
}
__device__ inline u16 f2h(float f) {
    _Float16 h = (_Float16)f;
    return __builtin_bit_cast(u16, h);
}
__device__ inline float h2f(u16 u) {
    return (float)__builtin_bit_cast(_Float16, u);
}
__device__ inline float fast_sigmoid(float x) {
    return __builtin_amdgcn_rcpf(1.f + __expf(-x));
}
__device__ inline float fast_tanh(float x) {
    return 1.f - 2.f * __builtin_amdgcn_rcpf(1.f + __expf(2.f * x));
}
__device__ inline f32x4 mfma16(s16x8 a, s16x8 b, f32x4 c) {
    return __builtin_amdgcn_mfma_f32_16x16x32_bf16(a, b, c, 0, 0, 0);
}

// ---------------- f32 -> bf16 convert (x) ----------------
__global__ void k_f2bf(const float* __restrict__ in, u16* __restrict__ out, int n) {
    int i = (blockIdx.x * 256 + threadIdx.x) * 4;
    if (i < n) {
        float4 v = *(const float4*)(in + i);
        ushort4 o;
        o.x = f2bf(v.x); o.y = f2bf(v.y); o.z = f2bf(v.z); o.w = f2bf(v.w);
        *(ushort4*)(out + i) = o;
    }
}

// ---------------- transpose + convert: out[c][r] = bf16(in[r][c]) ----------------
__global__ void k_transpose_bf(const float* __restrict__ in, u16* __restrict__ out,
                               int R, int C) {
    __shared__ float tile[32][33];
    int tid = threadIdx.x;
    int xs = (tid & 7) * 4;
    int y  = tid >> 3;
    int r0 = blockIdx.y * 32, c0 = blockIdx.x * 32;
    float4 v = *(const float4*)(in + (size_t)(r0 + y) * C + c0 + xs);
    tile[y][xs + 0] = v.x; tile[y][xs + 1] = v.y;
    tile[y][xs + 2] = v.z; tile[y][xs + 3] = v.w;
    __syncthreads();
    ushort4 o;
    o.x = f2bf(tile[xs + 0][y]); o.y = f2bf(tile[xs + 1][y]);
    o.z = f2bf(tile[xs + 2][y]); o.w = f2bf(tile[xs + 3][y]);
    *(ushort4*)(out + (size_t)(c0 + y) * R + r0 + xs) = o;
}

// ---------------- bf16 GEMM: C[m][n] = sum_k A[m][k] * BT[n][k] (+epilogue) ----------------
// MODE 0: xproj from [B,T]-major A: orow=(m&511)*32+(m>>9); write fp16 gate-interleaved.
// MODE 2: xproj from [T,B]-major A: orow=m;                 write fp16 gate-interleaved.
// MODE 1: heads from [T,B]-major A: orow=(m&31)*512+(m>>5);
//         n<256: softplus(acc+bias[n])+ymin[n] -> Cf[orow*256+n]
//         n>=256: acc+b2[n-256] -> Cf[4194304+orow*256+n-256]
template<int MODE>
__launch_bounds__(256, 2)
__global__ void k_gemm(const u16* __restrict__ A, const u16* __restrict__ BT,
                       const float* __restrict__ bias,
                       u16* __restrict__ Cb, float* __restrict__ Cf,
                       const float* __restrict__ b2, const float* __restrict__ ymin,
                       int gridN) {
    int bid = blockIdx.x;
    int m0 = (bid / gridN) * 128, n0 = (bid % gridN) * 128;
    __shared__ u16 As[128 * 40];
    __shared__ u16 Bs[128 * 40];
    int tid = threadIdx.x;
    int lane = tid & 63, w = tid >> 6;
    int wr = w >> 1, wc = w & 1;
    int rr = lane & 15, r16 = lane >> 4;
    f32x4 acc[4][4] = {};
    for (int kt = 0; kt < GK / 32; ++kt) {
        int k0 = kt * 32;
#pragma unroll
        for (int it = 0; it < 2; ++it) {
            int idx = it * 256 + tid;
            int row = idx >> 2, ch = idx & 3;
            *(u32x4*)(&As[row * 40 + ch * 8]) =
                *(const u32x4*)(A + (size_t)(m0 + row) * GK + k0 + ch * 8);
            *(u32x4*)(&Bs[row * 40 + ch * 8]) =
                *(const u32x4*)(BT + (size_t)(n0 + row) * GK + k0 + ch * 8);
        }
        __syncthreads();
        s16x8 af[4], bfr[4];
#pragma unroll
        for (int i = 0; i < 4; ++i) {
            int abase = (wr * 64 + i * 16 + rr) * 40 + r16 * 4;
            s16x4 lo = *(const s16x4*)(&As[abase]);
            s16x4 hi = *(const s16x4*)(&As[abase + 16]);
            af[i] = __builtin_shufflevector(lo, hi, 0, 1, 2, 3, 4, 5, 6, 7);
            int bbase = (wc * 64 + i * 16 + rr) * 40 + r16 * 4;
            s16x4 blo = *(const s16x4*)(&Bs[bbase]);
            s16x4 bhi = *(const s16x4*)(&Bs[bbase + 16]);
            bfr[i] = __builtin_shufflevector(blo, bhi, 0, 1, 2, 3, 4, 5, 6, 7);
        }
#pragma unroll
        for (int i = 0; i < 4; ++i)
#pragma unroll
            for (int j = 0; j < 4; ++j)
                acc[i][j] = mfma16(af[i], bfr[j], acc[i][j]);
        __syncthreads();
    }
#pragma unroll
    for (int i = 0; i < 4; ++i) {
#pragma unroll
        for (int j = 0; j < 4; ++j) {
#pragma unroll
            for (int r = 0; r < 4; ++r) {
                int m = m0 + wr * 64 + i * 16 + r16 * 4 + r;
                int n = n0 + wc * 64 + j * 16 + rr;
                float v = acc[i][j][r];
                if (MODE != 1) {
                    v += bias[n];
                    int orow = (MODE == 0) ? ((m & 511) * 32 + (m >> 9)) : m;
                    int colx = ((n & 1023) << 2) | (n >> 10);   // gate-interleaved
                    Cb[(size_t)orow * 4096 + colx] = f2h(v);
                } else {
                    int orow = (m & 31) * 512 + (m >> 5);
                    if (n < 256) {
                        v += bias[n];
                        float sp = fmaxf(v, 0.f) + log1pf(expf(-fabsf(v)));
                        Cf[(size_t)orow * 256 + n] = sp + ymin[n];
                    } else {
                        v += b2[n - 256];
                        Cf[4194304 + (size_t)orow * 256 + (n - 256)] = v;
                    }
                }
            }
        }
    }
}

// ---------------- persistent LSTM recurrence (fence-free, LDS-free) ----------------
// 128 blocks x 256 threads. Block owns 8 hidden units; wave w: mt=w>>1 (16 batches),
// nt=w&1 (4 units, gate-interleaved cols: c=4*u+g). Wh B-frags in registers.
// hseq: [513][32][1024] bf16; slot t+1 written at step t via sc1 stores; slot reads sc1.
__launch_bounds__(256)
__global__ void k_lstm(const u16* __restrict__ WhT, const u16* __restrict__ xproj,
                       u16* __restrict__ hseq, u32* __restrict__ flags) {
    int tid = threadIdx.x, blk = blockIdx.x;
    int lane = tid & 63, w = tid >> 6;
    int mt = w >> 1, nt = w & 1;
    int u0 = blk * 8;
    int rr = lane & 15, r16 = lane >> 4;

    // ---- Wh B-fragments (gate-interleaved cols), once ----
    int cg = (rr & 3) * 1024 + u0 + nt * 4 + (rr >> 2);   // global col: gate*1024 + unit
    const u16* wp = WhT + (size_t)cg * GK + r16 * 4;
    s16x8 bb[32];
#pragma unroll
    for (int kt = 0; kt < 32; ++kt) {
        s16x4 lo = *(const s16x4*)(wp + kt * 32);
        s16x4 hi = *(const s16x4*)(wp + kt * 32 + 16);
        bb[kt] = __builtin_shufflevector(lo, hi, 0, 1, 2, 3, 4, 5, 6, 7);
    }

    int b_   = mt * 16 + (lane >> 4) * 4 + (lane & 3);    // this lane's batch
    int unit = u0 + nt * 4 + ((lane >> 2) & 3);           // this lane's unit
    float c_reg = 0.f;
    const u16* xp_base = xproj + (size_t)b_ * 4096 + (size_t)unit * 4;

    for (int t = 0; t < 512; ++t) {
        // ---- wait: hseq[t] ready (flags >= t); per-wave poll, sc1 loads ----
        u32 tgt = (u32)t;
        while (true) {
            u32 v0 = __hip_atomic_load((u32*)&flags[lane], __ATOMIC_RELAXED,
                                       __HIP_MEMORY_SCOPE_AGENT);
            u32 v1 = __hip_atomic_load((u32*)&flags[64 + lane], __ATOMIC_RELAXED,
                                       __HIP_MEMORY_SCOPE_AGENT);
            if (__all((v0 >= tgt) & (v1 >= tgt))) break;
            __builtin_amdgcn_s_sleep(1);
        }
        __builtin_amdgcn_sched_barrier(0);

        u64 xv = *(const u64*)(xp_base + (size_t)t * 131072);  // 4 fp16 gates

        // ---- A-frags: global(sc1) -> registers, MFMA over K ----
        const u16* hb = hseq + (size_t)t * 32768 + (size_t)(mt * 16 + rr) * 1024 + r16 * 4;
        f32x4 accE = {}, accO = {};
#pragma unroll
        for (int kc = 0; kc < 4; ++kc) {
            u64 lo8[8], hi8[8];
#pragma unroll
            for (int q = 0; q < 8; ++q) {
                lo8[q] = __hip_atomic_load((u64*)(hb + (kc * 8 + q) * 32),
                                           __ATOMIC_RELAXED, __HIP_MEMORY_SCOPE_AGENT);
                hi8[q] = __hip_atomic_load((u64*)(hb + (kc * 8 + q) * 32 + 16),
                                           __ATOMIC_RELAXED, __HIP_MEMORY_SCOPE_AGENT);
            }
#pragma unroll
            for (int q = 0; q < 8; ++q) {
                s16x4 l4 = __builtin_bit_cast(s16x4, lo8[q]);
                s16x4 h4 = __builtin_bit_cast(s16x4, hi8[q]);
                s16x8 a = __builtin_shufflevector(l4, h4, 0, 1, 2, 3, 4, 5, 6, 7);
                if (q & 1) accO = mfma16(a, bb[kc * 8 + q], accO);
                else       accE = mfma16(a, bb[kc * 8 + q], accE);
            }
        }
        f32x4 acc = accE + accO;

        // ---- 4x4 lane-quad transpose: lane gets (i,f,g,o) of its (b,unit) ----
        float r0 = acc[0], r1 = acc[1], r2 = acc[2], r3 = acc[3];
        float x0 = __shfl_xor(r0, 1), x1 = __shfl_xor(r1, 1);
        float x2 = __shfl_xor(r2, 1), x3 = __shfl_xor(r3, 1);
        bool o1 = lane & 1;
        float s0 = o1 ? x1 : r0;
        float s1 = o1 ? r1 : x0;
        float s2 = o1 ? x3 : r2;
        float s3 = o1 ? r3 : x2;
        float y0 = __shfl_xor(s0, 2), y1 = __shfl_xor(s1, 2);
        float y2 = __shfl_xor(s2, 2), y3 = __shfl_xor(s3, 2);
        bool o2 = lane & 2;
        float gi = o2 ? y2 : s0;
        float gf = o2 ? y3 : s1;
        float gg = o2 ? s2 : y0;
        float go = o2 ? s3 : y1;

        gi += h2f((u16)(xv));
        gf += h2f((u16)(xv >> 16));
        gg += h2f((u16)(xv >> 32));
        go += h2f((u16)(xv >> 48));

        float I  = fast_sigmoid(gi);
        float Fg = fast_sigmoid(gf);
        float G  = fast_tanh(gg);
        float O  = fast_sigmoid(go);
        c_reg = Fg * c_reg + I * G;
        float h = O * fast_tanh(c_reg);

        __hip_atomic_store(hseq + (size_t)(t + 1) * 32768 + (size_t)b_ * 1024 + unit,
                           f2bf(h), __ATOMIC_RELAXED, __HIP_MEMORY_SCOPE_AGENT);
        __syncthreads();   // drains vmcnt: all waves' h stores acked at coherence point
        if (tid == 0)
            __hip_atomic_store(&flags[blk], (u32)(t + 1), __ATOMIC_RELAXED,
                               __HIP_MEMORY_SCOPE_AGENT);
    }
}

extern "C" void kernel_launch(void* const* d_in, const int* in_sizes, int n_in,
                              void* d_out, int out_size, void* d_ws, size_t ws_size,
                              hipStream_t stream) {
    const float* x   = (const float*)d_in[0];
    const float* Wx  = (const float*)d_in[1];
    const float* Wh  = (const float*)d_in[2];
    const float* b   = (const float*)d_in[3];
    const float* Wmu = (const float*)d_in[4];
    const float* bmu = (const float*)d_in[5];
    const float* Wls = (const float*)d_in[6];
    const float* bls = (const float*)d_in[7];
    const float* ym  = (const float*)d_in[8];
    float* out = (float*)d_out;

    // workspace layout (236,061,696 B total):
    // [0)            hseq2 [513][32][1024] (33,619,968 B)  -- aliases xbf (32 MiB)
    // [33,619,968)   wxT   (16,777,216 B)
    // [50,397,184)   whT   (16,777,216 B)
    // [67,174,400)   whdT  (1,048,576 B)
    // [68,222,976)   xproj (134,217,728 B) fp16 gate-interleaved [T*B][4096]
    // [202,440,704)  hseq1 [513][32][1024] (33,619,968 B)
    // [236,060,672)  flags0/flags1 (1,024 B)
    char* ws = (char*)d_ws;
    u16* hseq2  = (u16*)(ws);
    u16* xbf    = (u16*)(ws);
    u16* wxT    = (u16*)(ws + 33619968);
    u16* whT    = (u16*)(ws + 50397184);
    u16* whdT   = (u16*)(ws + 67174400);
    u16* xproj  = (u16*)(ws + 68222976);
    u16* hseq1  = (u16*)(ws + 202440704);
    u32* flags0 = (u32*)(ws + 236060672);
    u32* flags1 = (u32*)(ws + 236061184);

    // zero flags + hseq1 slot0
    hipMemsetAsync(flags0, 0, 1024, stream);
    hipMemsetAsync(hseq1, 0, 65536, stream);

    // prep: conversions / transposes
    k_f2bf<<<16384, 256, 0, stream>>>(x, xbf, 16777216);
    dim3 tg(128, 32);
    k_transpose_bf<<<tg, 256, 0, stream>>>(Wx,           wxT,           1024, 4096);
    k_transpose_bf<<<tg, 256, 0, stream>>>(Wx + 4194304, wxT + 4194304, 1024, 4096);
    k_transpose_bf<<<tg, 256, 0, stream>>>(Wh,           whT,           1024, 4096);
    k_transpose_bf<<<tg, 256, 0, stream>>>(Wh + 4194304, whT + 4194304, 1024, 4096);
    dim3 hg(8, 32);
    k_transpose_bf<<<hg, 256, 0, stream>>>(Wmu, whdT,          1024, 256);
    k_transpose_bf<<<hg, 256, 0, stream>>>(Wls, whdT + 262144, 1024, 256);

    // layer 0: xproj from x ([B,T]-major) then recurrence into hseq1
    k_gemm<0><<<4096, 256, 0, stream>>>(xbf, wxT, b, xproj, nullptr, nullptr, nullptr, 32);
    k_lstm<<<128, 256, 0, stream>>>(whT, xproj, hseq1, flags0);

    // layer 1: xproj from hseq1 ([T,B]-major), recurrence into hseq2 (aliases dead xbf)
    hipMemsetAsync(hseq2, 0, 65536, stream);
    k_gemm<2><<<4096, 256, 0, stream>>>(hseq1 + 32768, wxT + 4194304, b + 4096, xproj,
                                        nullptr, nullptr, nullptr, 32);
    k_lstm<<<128, 256, 0, stream>>>(whT + 4194304, xproj, hseq2, flags1);

    // heads (mu || log_sigma) from hseq2 ([T,B]-major)
    k_gemm<1><<<512, 256, 0, stream>>>(hseq2 + 32768, whdT, bmu, nullptr, out, bls, ym, 4);
}

// Round 4
// 11421.793 us; speedup vs baseline: 1.0598x; 1.0598x over previous
//
#include <hip/hip_runtime.h>

typedef unsigned short u16;
typedef unsigned int   u32;
typedef unsigned long long u64;
typedef short s16x4 __attribute__((ext_vector_type(4)));
typedef short s16x8 __attribute__((ext_vector_type(8)));
typedef float f32x4 __attribute__((ext_vector_type(4)));
typedef u32   u32x4 __attribute__((ext_vector_type(4)));

#define GK 1024

__device__ inline u16 f2bf(float f) {
    u32 u = __builtin_bit_cast(u32, f);
    u += 0x7FFFu + ((u >> 16) & 1u);
    return (u16)(u >> 16);
}
__device__ inline u16 f2h(float f) {
    _Float16 h = (_Float16)f;
    return __builtin_bit_cast(u16, h);
}
__device__ inline float h2f(u16 u) {
    return (float)__builtin_bit_cast(_Float16, u);
}
__device__ inline float fast_sigmoid(float x) {
    return __builtin_amdgcn_rcpf(1.f + __expf(-x));
}
__device__ inline float fast_tanh(float x) {
    return 1.f - 2.f * __builtin_amdgcn_rcpf(1.f + __expf(2.f * x));
}
__device__ inline f32x4 mfma16(s16x8 a, s16x8 b, f32x4 c) {
    return __builtin_amdgcn_mfma_f32_16x16x32_bf16(a, b, c, 0, 0, 0);
}
__device__ inline s16x8 mk8(s16x4 lo, s16x4 hi) {
    return __builtin_shufflevector(lo, hi, 0, 1, 2, 3, 4, 5, 6, 7);
}

// ---------------- f32 -> bf16 convert (x) ----------------
__global__ void k_f2bf(const float* __restrict__ in, u16* __restrict__ out, int n) {
    int i = (blockIdx.x * 256 + threadIdx.x) * 4;
    if (i < n) {
        float4 v = *(const float4*)(in + i);
        ushort4 o;
        o.x = f2bf(v.x); o.y = f2bf(v.y); o.z = f2bf(v.z); o.w = f2bf(v.w);
        *(ushort4*)(out + i) = o;
    }
}

// ---------------- transpose + convert: out[c][r] = bf16(in[r][c]) ----------------
__global__ void k_transpose_bf(const float* __restrict__ in, u16* __restrict__ out,
                               int R, int C) {
    __shared__ float tile[32][33];
    int tid = threadIdx.x;
    int xs = (tid & 7) * 4;
    int y  = tid >> 3;
    int r0 = blockIdx.y * 32, c0 = blockIdx.x * 32;
    float4 v = *(const float4*)(in + (size_t)(r0 + y) * C + c0 + xs);
    tile[y][xs + 0] = v.x; tile[y][xs + 1] = v.y;
    tile[y][xs + 2] = v.z; tile[y][xs + 3] = v.w;
    __syncthreads();
    ushort4 o;
    o.x = f2bf(tile[xs + 0][y]); o.y = f2bf(tile[xs + 1][y]);
    o.z = f2bf(tile[xs + 2][y]); o.w = f2bf(tile[xs + 3][y]);
    *(ushort4*)(out + (size_t)(c0 + y) * R + r0 + xs) = o;
}

// ---------------- bf16 GEMM: C[m][n] = sum_k A[m][k] * BT[n][k] (+epilogue) ----------------
// MODE 0: A plain [M][1024]; write fp16 gate-interleaved xproj at orow=(m&511)*32+(m>>9).
// MODE 1: A in hseq layout [t][kb(128)][b(32)][u(8)] (base = slot 1): heads epilogue,
//         orow=(m&31)*512+(m>>5): n<256 softplus+ymin -> mu; n>=256 -> log_sigma.
template<int MODE>
__launch_bounds__(256, 2)
__global__ void k_gemm(const u16* __restrict__ A, const u16* __restrict__ BT,
                       const float* __restrict__ bias,
                       u16* __restrict__ Cb, float* __restrict__ Cf,
                       const float* __restrict__ b2, const float* __restrict__ ymin,
                       int gridN) {
    int bid = blockIdx.x;
    int m0 = (bid / gridN) * 128, n0 = (bid % gridN) * 128;
    __shared__ u16 As[128 * 40];
    __shared__ u16 Bs[128 * 40];
    int tid = threadIdx.x;
    int lane = tid & 63, w = tid >> 6;
    int wr = w >> 1, wc = w & 1;
    int rr = lane & 15, r16 = lane >> 4;
    f32x4 acc[4][4] = {};
    for (int kt = 0; kt < GK / 32; ++kt) {
        int k0 = kt * 32;
#pragma unroll
        for (int it = 0; it < 2; ++it) {
            int idx = it * 256 + tid;
            int row = idx >> 2, ch = idx & 3;
            if (MODE == 0) {
                *(u32x4*)(&As[row * 40 + ch * 8]) =
                    *(const u32x4*)(A + (size_t)(m0 + row) * GK + k0 + ch * 8);
            } else {
                int m = m0 + row;
                size_t aaddr = (size_t)(m >> 5) * 32768 + (size_t)((k0 >> 3) + ch) * 256
                             + (size_t)(m & 31) * 8;
                *(u32x4*)(&As[row * 40 + ch * 8]) = *(const u32x4*)(A + aaddr);
            }
            *(u32x4*)(&Bs[row * 40 + ch * 8]) =
                *(const u32x4*)(BT + (size_t)(n0 + row) * GK + k0 + ch * 8);
        }
        __syncthreads();
        s16x8 af[4], bfr[4];
#pragma unroll
        for (int i = 0; i < 4; ++i) {
            int abase = (wr * 64 + i * 16 + rr) * 40 + r16 * 4;
            af[i] = mk8(*(const s16x4*)(&As[abase]), *(const s16x4*)(&As[abase + 16]));
            int bbase = (wc * 64 + i * 16 + rr) * 40 + r16 * 4;
            bfr[i] = mk8(*(const s16x4*)(&Bs[bbase]), *(const s16x4*)(&Bs[bbase + 16]));
        }
#pragma unroll
        for (int i = 0; i < 4; ++i)
#pragma unroll
            for (int j = 0; j < 4; ++j)
                acc[i][j] = mfma16(af[i], bfr[j], acc[i][j]);
        __syncthreads();
    }
#pragma unroll
    for (int i = 0; i < 4; ++i) {
#pragma unroll
        for (int j = 0; j < 4; ++j) {
#pragma unroll
            for (int r = 0; r < 4; ++r) {
                int m = m0 + wr * 64 + i * 16 + r16 * 4 + r;
                int n = n0 + wc * 64 + j * 16 + rr;
                float v = acc[i][j][r];
                if (MODE == 0) {
                    v += bias[n];
                    int orow = (m & 511) * 32 + (m >> 9);
                    int colx = ((n & 1023) << 2) | (n >> 10);   // gate-interleaved
                    Cb[(size_t)orow * 4096 + colx] = f2h(v);
                } else {
                    int orow = (m & 31) * 512 + (m >> 5);
                    if (n < 256) {
                        v += bias[n];
                        float sp = fmaxf(v, 0.f) + log1pf(expf(-fabsf(v)));
                        Cf[(size_t)orow * 256 + n] = sp + ymin[n];
                    } else {
                        v += b2[n - 256];
                        Cf[4194304 + (size_t)orow * 256 + (n - 256)] = v;
                    }
                }
            }
        }
    }
}

// ---------------- fused 2-layer persistent LSTM recurrence ----------------
// 128 blocks x 256 threads; block owns units [blk*8, blk*8+8) of BOTH layers.
// hseq{0,1}: [513][kb(128)][b(32)][u(8)] u16. Round r: L0 computes h0 slot r+1
// (consumes xproj[t=r], hseq0[r]); L1 computes h1 slot r (consumes hseq0[r],
// hseq1[r-1], streamed Wx1). One flag barrier per round; 513 rounds.
__launch_bounds__(256, 1)
__global__ void k_fused(const u16* __restrict__ Wh0T, const u16* __restrict__ Wx1T,
                        const u16* __restrict__ Wh1T, const u16* __restrict__ xproj,
                        const float* __restrict__ b1,
                        u16* __restrict__ hseq0, u16* __restrict__ hseq1,
                        u32* __restrict__ flags) {
    int tid = threadIdx.x, blk = blockIdx.x;
    int lane = tid & 63, w = tid >> 6;
    int mt = w >> 1, nt = w & 1;
    int u0 = blk * 8;
    int rr = lane & 15, r16 = lane >> 4;

    // B-frag column for this lane: gate = rr&3, unit = u0 + nt*4 + (rr>>2)
    int cg = (rr & 3) * 1024 + u0 + nt * 4 + (rr >> 2);
    const u16* wp0 = Wh0T + (size_t)cg * GK + r16 * 4;
    const u16* wph = Wh1T + (size_t)cg * GK + r16 * 4;
    u64 wpx_u = (u64)(uintptr_t)(Wx1T + (size_t)cg * GK + r16 * 4);

    s16x8 bb0[32], bbh[32];
#pragma unroll
    for (int q = 0; q < 32; ++q) {
        bb0[q] = mk8(*(const s16x4*)(wp0 + q * 32), *(const s16x4*)(wp0 + q * 32 + 16));
        bbh[q] = mk8(*(const s16x4*)(wph + q * 32), *(const s16x4*)(wph + q * 32 + 16));
    }

    int b_    = mt * 16 + (lane >> 4) * 4 + (lane & 3);
    int u_loc = nt * 4 + ((lane >> 2) & 3);
    int unit  = u0 + u_loc;
    float c0 = 0.f, c1 = 0.f;
    float b1r[4];
#pragma unroll
    for (int g = 0; g < 4; ++g) b1r[g] = b1[g * 1024 + unit];

    const u16* xp = xproj + (size_t)b_ * 4096 + (size_t)unit * 4;  // + t*131072
    const int boff = (mt * 16 + rr) * 8 + (r16 & 1) * 4;   // elem offset within slot
    const int kq   = (r16 >> 1);                           // kb sub-offset per q
    // leader store offsets (elements within slot)
    const int soff = blk * 256 + b_ * 8 + nt * 4;

    for (int r = 0; r <= 512; ++r) {
        // ---- barrier: wait all 128 flags >= r ----
        u32 tgt = (u32)r;
        while (true) {
            u32 v0 = __hip_atomic_load(&flags[lane], __ATOMIC_RELAXED,
                                       __HIP_MEMORY_SCOPE_AGENT);
            u32 v1 = __hip_atomic_load(&flags[64 + lane], __ATOMIC_RELAXED,
                                       __HIP_MEMORY_SCOPE_AGENT);
            if (__all((v0 >= tgt) & (v1 >= tgt))) break;
            __builtin_amdgcn_s_sleep(1);
        }
        __builtin_amdgcn_sched_barrier(0);

        u64 xv = 0;
        if (r < 512) xv = *(const u64*)(xp + (size_t)r * 131072);

        // ---- A-frags from hseq0[r]; feed L0 (bb0) and L1-x (streamed Wx1) ----
        asm volatile("" : "+v"(wpx_u));   // defeat LICM of the Wx1 stream loads
        const u16* wpx = (const u16*)(uintptr_t)wpx_u;
        const u16* h0p = hseq0 + (size_t)r * 32768 + boff;
        f32x4 aE = {}, aO = {}, hE = {}, hO = {};
#pragma unroll
        for (int q = 0; q < 32; ++q) {
            u64 lo = __hip_atomic_load((const u64*)(h0p + (q * 4 + kq) * 256),
                                       __ATOMIC_RELAXED, __HIP_MEMORY_SCOPE_AGENT);
            u64 hi = __hip_atomic_load((const u64*)(h0p + (q * 4 + kq + 2) * 256),
                                       __ATOMIC_RELAXED, __HIP_MEMORY_SCOPE_AGENT);
            s16x8 a = mk8(__builtin_bit_cast(s16x4, lo), __builtin_bit_cast(s16x4, hi));
            s16x8 bx = mk8(*(const s16x4*)(wpx + q * 32),
                           *(const s16x4*)(wpx + q * 32 + 16));
            if (q & 1) { aO = mfma16(a, bb0[q], aO); hO = mfma16(a, bx, hO); }
            else       { aE = mfma16(a, bb0[q], aE); hE = mfma16(a, bx, hE); }
        }
        // ---- L1 recurrent part from hseq1[r-1] ----
        if (r > 0) {
            const u16* h1p = hseq1 + (size_t)(r - 1) * 32768 + boff;
#pragma unroll
            for (int q = 0; q < 32; ++q) {
                u64 lo = __hip_atomic_load((const u64*)(h1p + (q * 4 + kq) * 256),
                                           __ATOMIC_RELAXED, __HIP_MEMORY_SCOPE_AGENT);
                u64 hi = __hip_atomic_load((const u64*)(h1p + (q * 4 + kq + 2) * 256),
                                           __ATOMIC_RELAXED, __HIP_MEMORY_SCOPE_AGENT);
                s16x8 a = mk8(__builtin_bit_cast(s16x4, lo),
                              __builtin_bit_cast(s16x4, hi));
                if (q & 1) hO = mfma16(a, bbh[q], hO);
                else       hE = mfma16(a, bbh[q], hE);
            }
        }

        // ---- L0 epilogue: transpose quad -> (i,f,g,o), nonlin, pack, store ----
        if (r < 512) {
            f32x4 acc = aE + aO;
            float r0 = acc[0], r1 = acc[1], r2 = acc[2], r3 = acc[3];
            float x0 = __shfl_xor(r0, 1), x1 = __shfl_xor(r1, 1);
            float x2 = __shfl_xor(r2, 1), x3 = __shfl_xor(r3, 1);
            bool o1 = lane & 1;
            float s0 = o1 ? x1 : r0, s1 = o1 ? r1 : x0;
            float s2 = o1 ? x3 : r2, s3 = o1 ? r3 : x2;
            float y0 = __shfl_xor(s0, 2), y1 = __shfl_xor(s1, 2);
            float y2 = __shfl_xor(s2, 2), y3 = __shfl_xor(s3, 2);
            bool o2 = lane & 2;
            float gi = (o2 ? y2 : s0) + h2f((u16)(xv));
            float gf = (o2 ? y3 : s1) + h2f((u16)(xv >> 16));
            float gg = (o2 ? s2 : y0) + h2f((u16)(xv >> 32));
            float go = (o2 ? s3 : y1) + h2f((u16)(xv >> 48));
            float I  = fast_sigmoid(gi);
            float Fg = fast_sigmoid(gf);
            float G  = fast_tanh(gg);
            float O  = fast_sigmoid(go);
            c0 = Fg * c0 + I * G;
            u32 hq = (u32)f2bf(O * fast_tanh(c0));
            u32 o4 = (u32)__shfl_xor((int)hq, 4);
            u32 m32 = (lane & 4) ? ((o4 & 0xffffu) | (hq << 16))
                                 : ((hq & 0xffffu) | (o4 << 16));
            u32 o8 = (u32)__shfl_xor((int)m32, 8);
            u64 m64 = (lane & 8) ? (((u64)o8) | ((u64)m32 << 32))
                                 : (((u64)m32) | ((u64)o8 << 32));
            if ((lane & 12) == 0)
                __hip_atomic_store((u64*)(hseq0 + (size_t)(r + 1) * 32768 + soff), m64,
                                   __ATOMIC_RELAXED, __HIP_MEMORY_SCOPE_AGENT);
        }
        // ---- L1 epilogue ----
        if (r > 0) {
            f32x4 acc = hE + hO;
            float r0 = acc[0], r1 = acc[1], r2 = acc[2], r3 = acc[3];
            float x0 = __shfl_xor(r0, 1), x1 = __shfl_xor(r1, 1);
            float x2 = __shfl_xor(r2, 1), x3 = __shfl_xor(r3, 1);
            bool o1 = lane & 1;
            float s0 = o1 ? x1 : r0, s1 = o1 ? r1 : x0;
            float s2 = o1 ? x3 : r2, s3 = o1 ? r3 : x2;
            float y0 = __shfl_xor(s0, 2), y1 = __shfl_xor(s1, 2);
            float y2 = __shfl_xor(s2, 2), y3 = __shfl_xor(s3, 2);
            bool o2 = lane & 2;
            float gi = (o2 ? y2 : s0) + b1r[0];
            float gf = (o2 ? y3 : s1) + b1r[1];
            float gg = (o2 ? s2 : y0) + b1r[2];
            float go = (o2 ? s3 : y1) + b1r[3];
            float I  = fast_sigmoid(gi);
            float Fg = fast_sigmoid(gf);
            float G  = fast_tanh(gg);
            float O  = fast_sigmoid(go);
            c1 = Fg * c1 + I * G;
            u32 hq = (u32)f2bf(O * fast_tanh(c1));
            u32 o4 = (u32)__shfl_xor((int)hq, 4);
            u32 m32 = (lane & 4) ? ((o4 & 0xffffu) | (hq << 16))
                                 : ((hq & 0xffffu) | (o4 << 16));
            u32 o8 = (u32)__shfl_xor((int)m32, 8);
            u64 m64 = (lane & 8) ? (((u64)o8) | ((u64)m32 << 32))
                                 : (((u64)m32) | ((u64)o8 << 32));
            if ((lane & 12) == 0)
                __hip_atomic_store((u64*)(hseq1 + (size_t)r * 32768 + soff), m64,
                                   __ATOMIC_RELAXED, __HIP_MEMORY_SCOPE_AGENT);
        }
        __syncthreads();   // drains vmcnt: all 4 waves' sc1 stores acked
        if (tid == 0)
            __hip_atomic_store(&flags[blk], (u32)(r + 1), __ATOMIC_RELAXED,
                               __HIP_MEMORY_SCOPE_AGENT);
    }
}

extern "C" void kernel_launch(void* const* d_in, const int* in_sizes, int n_in,
                              void* d_out, int out_size, void* d_ws, size_t ws_size,
                              hipStream_t stream) {
    const float* x   = (const float*)d_in[0];
    const float* Wx  = (const float*)d_in[1];
    const float* Wh  = (const float*)d_in[2];
    const float* b   = (const float*)d_in[3];
    const float* Wmu = (const float*)d_in[4];
    const float* bmu = (const float*)d_in[5];
    const float* Wls = (const float*)d_in[6];
    const float* bls = (const float*)d_in[7];
    const float* ym  = (const float*)d_in[8];
    float* out = (float*)d_out;

    // workspace (236,061,184 B):
    // [0)            hseq0 [513][32768] u16 = 33,619,968  (aliases xbf 32 MiB)
    // [33,619,968)   hseq1 33,619,968
    // [67,239,936)   wxT   16,777,216   [2][4096][1024]
    // [84,017,152)   whT   16,777,216
    // [100,794,368)  whdT   1,048,576   [512][1024]
    // [101,842,944)  xproj 134,217,728  fp16 gate-interleaved [T*32+b][4096]
    // [236,060,672)  flags 512
    char* ws = (char*)d_ws;
    u16* hseq0 = (u16*)(ws);
    u16* xbf   = (u16*)(ws);
    u16* hseq1 = (u16*)(ws + 33619968);
    u16* wxT   = (u16*)(ws + 67239936);
    u16* whT   = (u16*)(ws + 84017152);
    u16* whdT  = (u16*)(ws + 100794368);
    u16* xproj = (u16*)(ws + 101842944);
    u32* flags = (u32*)(ws + 236060672);

    // prep
    k_f2bf<<<16384, 256, 0, stream>>>(x, xbf, 16777216);
    dim3 tg(128, 32);
    k_transpose_bf<<<tg, 256, 0, stream>>>(Wx,           wxT,           1024, 4096);
    k_transpose_bf<<<tg, 256, 0, stream>>>(Wx + 4194304, wxT + 4194304, 1024, 4096);
    k_transpose_bf<<<tg, 256, 0, stream>>>(Wh,           whT,           1024, 4096);
    k_transpose_bf<<<tg, 256, 0, stream>>>(Wh + 4194304, whT + 4194304, 1024, 4096);
    dim3 hg(8, 32);
    k_transpose_bf<<<hg, 256, 0, stream>>>(Wmu, whdT,          1024, 256);
    k_transpose_bf<<<hg, 256, 0, stream>>>(Wls, whdT + 262144, 1024, 256);

    // layer-0 x-projection (reads xbf, writes xproj)
    k_gemm<0><<<4096, 256, 0, stream>>>(xbf, wxT, b, xproj, nullptr, nullptr, nullptr, 32);

    // zero initial h slots + flags (xbf is dead now; hseq0 aliases it)
    hipMemsetAsync(hseq0, 0, 65536, stream);
    hipMemsetAsync(hseq1, 0, 65536, stream);
    hipMemsetAsync(flags, 0, 512, stream);

    // fused 2-layer recurrence
    k_fused<<<128, 256, 0, stream>>>(whT, wxT + 4194304, whT + 4194304, xproj,
                                     b + 4096, hseq0, hseq1, flags);

    // heads (mu || log_sigma) from hseq1 slots 1..512
    k_gemm<1><<<512, 256, 0, stream>>>(hseq1 + 32768, whdT, bmu, nullptr, out,
                                       bls, ym, 4);
}

// Round 5
// 8160.857 us; speedup vs baseline: 1.4833x; 1.3996x over previous
//
#include <hip/hip_runtime.h>

typedef unsigned short u16;
typedef unsigned int   u32;
typedef unsigned long long u64;
typedef short s16x4 __attribute__((ext_vector_type(4)));
typedef short s16x8 __attribute__((ext_vector_type(8)));
typedef float f32x4 __attribute__((ext_vector_type(4)));
typedef u32   u32x4 __attribute__((ext_vector_type(4)));

#define GK 1024

__device__ inline u16 f2bf(float f) {
    u32 u = __builtin_bit_cast(u32, f);
    u += 0x7FFFu + ((u >> 16) & 1u);
    return (u16)(u >> 16);
}
__device__ inline u16 f2h(float f) {
    _Float16 h = (_Float16)f;
    return __builtin_bit_cast(u16, h);
}
__device__ inline float h2f(u16 u) {
    return (float)__builtin_bit_cast(_Float16, u);
}
__device__ inline float fast_sigmoid(float x) {
    return __builtin_amdgcn_rcpf(1.f + __expf(-x));
}
__device__ inline float fast_tanh(float x) {
    return 1.f - 2.f * __builtin_amdgcn_rcpf(1.f + __expf(2.f * x));
}
__device__ inline f32x4 mfma16(s16x8 a, s16x8 b, f32x4 c) {
    return __builtin_amdgcn_mfma_f32_16x16x32_bf16(a, b, c, 0, 0, 0);
}
__device__ inline s16x8 mk8(s16x4 lo, s16x4 hi) {
    return __builtin_shufflevector(lo, hi, 0, 1, 2, 3, 4, 5, 6, 7);
}

// ---------------- f32 -> bf16 convert (x) ----------------
__global__ void k_f2bf(const float* __restrict__ in, u16* __restrict__ out, int n) {
    int i = (blockIdx.x * 256 + threadIdx.x) * 4;
    if (i < n) {
        float4 v = *(const float4*)(in + i);
        ushort4 o;
        o.x = f2bf(v.x); o.y = f2bf(v.y); o.z = f2bf(v.z); o.w = f2bf(v.w);
        *(ushort4*)(out + i) = o;
    }
}

// ---------------- transpose + convert: out[c][r] = bf16(in[r][c]) ----------------
__global__ void k_transpose_bf(const float* __restrict__ in, u16* __restrict__ out,
                               int R, int C) {
    __shared__ float tile[32][33];
    int tid = threadIdx.x;
    int xs = (tid & 7) * 4;
    int y  = tid >> 3;
    int r0 = blockIdx.y * 32, c0 = blockIdx.x * 32;
    float4 v = *(const float4*)(in + (size_t)(r0 + y) * C + c0 + xs);
    tile[y][xs + 0] = v.x; tile[y][xs + 1] = v.y;
    tile[y][xs + 2] = v.z; tile[y][xs + 3] = v.w;
    __syncthreads();
    ushort4 o;
    o.x = f2bf(tile[xs + 0][y]); o.y = f2bf(tile[xs + 1][y]);
    o.z = f2bf(tile[xs + 2][y]); o.w = f2bf(tile[xs + 3][y]);
    *(ushort4*)(out + (size_t)(c0 + y) * R + r0 + xs) = o;
}

// ---------------- bf16 GEMM: C[m][n] = sum_k A[m][k] * BT[n][k] (+epilogue) ----------------
// MODE 0: A plain [M][1024]; write fp16 gate-interleaved xproj at orow=(m&511)*32+(m>>9).
// MODE 1: A in hseq layout [t][kb(128)][b(32)][u(8)] (base = slot 1): heads epilogue,
//         orow=(m&31)*512+(m>>5): n<256 softplus+ymin -> mu; n>=256 -> log_sigma.
template<int MODE>
__launch_bounds__(256, 2)
__global__ void k_gemm(const u16* __restrict__ A, const u16* __restrict__ BT,
                       const float* __restrict__ bias,
                       u16* __restrict__ Cb, float* __restrict__ Cf,
                       const float* __restrict__ b2, const float* __restrict__ ymin,
                       int gridN) {
    int bid = blockIdx.x;
    int m0 = (bid / gridN) * 128, n0 = (bid % gridN) * 128;
    __shared__ u16 As[128 * 40];
    __shared__ u16 Bs[128 * 40];
    int tid = threadIdx.x;
    int lane = tid & 63, w = tid >> 6;
    int wr = w >> 1, wc = w & 1;
    int rr = lane & 15, r16 = lane >> 4;
    f32x4 acc[4][4] = {};
    for (int kt = 0; kt < GK / 32; ++kt) {
        int k0 = kt * 32;
#pragma unroll
        for (int it = 0; it < 2; ++it) {
            int idx = it * 256 + tid;
            int row = idx >> 2, ch = idx & 3;
            if (MODE == 0) {
                *(u32x4*)(&As[row * 40 + ch * 8]) =
                    *(const u32x4*)(A + (size_t)(m0 + row) * GK + k0 + ch * 8);
            } else {
                int m = m0 + row;
                size_t aaddr = (size_t)(m >> 5) * 32768 + (size_t)((k0 >> 3) + ch) * 256
                             + (size_t)(m & 31) * 8;
                *(u32x4*)(&As[row * 40 + ch * 8]) = *(const u32x4*)(A + aaddr);
            }
            *(u32x4*)(&Bs[row * 40 + ch * 8]) =
                *(const u32x4*)(BT + (size_t)(n0 + row) * GK + k0 + ch * 8);
        }
        __syncthreads();
        s16x8 af[4], bfr[4];
#pragma unroll
        for (int i = 0; i < 4; ++i) {
            int abase = (wr * 64 + i * 16 + rr) * 40 + r16 * 4;
            af[i] = mk8(*(const s16x4*)(&As[abase]), *(const s16x4*)(&As[abase + 16]));
            int bbase = (wc * 64 + i * 16 + rr) * 40 + r16 * 4;
            bfr[i] = mk8(*(const s16x4*)(&Bs[bbase]), *(const s16x4*)(&Bs[bbase + 16]));
        }
#pragma unroll
        for (int i = 0; i < 4; ++i)
#pragma unroll
            for (int j = 0; j < 4; ++j)
                acc[i][j] = mfma16(af[i], bfr[j], acc[i][j]);
        __syncthreads();
    }
#pragma unroll
    for (int i = 0; i < 4; ++i) {
#pragma unroll
        for (int j = 0; j < 4; ++j) {
#pragma unroll
            for (int r = 0; r < 4; ++r) {
                int m = m0 + wr * 64 + i * 16 + r16 * 4 + r;
                int n = n0 + wc * 64 + j * 16 + rr;
                float v = acc[i][j][r];
                if (MODE == 0) {
                    v += bias[n];
                    int orow = (m & 511) * 32 + (m >> 9);
                    int colx = ((n & 1023) << 2) | (n >> 10);   // gate-interleaved
                    Cb[(size_t)orow * 4096 + colx] = f2h(v);
                } else {
                    int orow = (m & 31) * 512 + (m >> 5);
                    if (n < 256) {
                        v += bias[n];
                        float sp = fmaxf(v, 0.f) + log1pf(expf(-fabsf(v)));
                        Cf[(size_t)orow * 256 + n] = sp + ymin[n];
                    } else {
                        v += b2[n - 256];
                        Cf[4194304 + (size_t)orow * 256 + (n - 256)] = v;
                    }
                }
            }
        }
    }
}

// ---------------- fused 2-layer persistent LSTM, wave-group split ----------------
// 128 blocks x 512 threads (8 waves). Group A = waves 0-3: layer 0 (static Wh0
// frags) + layer-1 x-path (Wx1 frags streamed from L2, reusing the h0 A-frags)
// + both epilogues/stores. Group B = waves 4-7: layer-1 recurrent matmul (static
// Wh1 frags) -> partial via LDS to group A. One flag barrier per round.
__launch_bounds__(512, 2)
__global__ void k_fused(const u16* __restrict__ Wh0T, const u16* __restrict__ Wx1T,
                        const u16* __restrict__ Wh1T, const u16* __restrict__ xproj,
                        const float* __restrict__ b1,
                        u16* __restrict__ hseq0, u16* __restrict__ hseq1,
                        u32* __restrict__ flags) {
    __shared__ float part[4][64][4];
    int tid = threadIdx.x, blk = blockIdx.x;
    int lane = tid & 63, w = tid >> 6;
    int grp = w >> 2, wl = w & 3;
    int mt = wl >> 1, nt = wl & 1;
    int u0 = blk * 8;
    int rr = lane & 15, r16 = lane >> 4;

    // static B-frags: group A holds Wh0, group B holds Wh1 (128 VGPRs each)
    int cg = (rr & 3) * 1024 + u0 + nt * 4 + (rr >> 2);
    const u16* wstat = (grp == 0 ? Wh0T : Wh1T) + (size_t)cg * GK + r16 * 4;
    u64 wpx_u = (u64)(uintptr_t)(Wx1T + (size_t)cg * GK + r16 * 4);
    s16x8 bstat[32];
#pragma unroll
    for (int q = 0; q < 32; ++q)
        bstat[q] = mk8(*(const s16x4*)(wstat + q * 32),
                       *(const s16x4*)(wstat + q * 32 + 16));

    int b_    = mt * 16 + (lane >> 4) * 4 + (lane & 3);
    int u_loc = nt * 4 + ((lane >> 2) & 3);
    int unit  = u0 + u_loc;
    float c0 = 0.f, c1 = 0.f;
    float b1r[4];
#pragma unroll
    for (int g = 0; g < 4; ++g) b1r[g] = b1[g * 1024 + unit];

    const u16* xp = xproj + (size_t)b_ * 4096 + (size_t)unit * 4;
    const int boff = (mt * 16 + rr) * 8 + (r16 & 1) * 4;
    const int kq   = (r16 >> 1);
    const int soff = blk * 256 + b_ * 8 + nt * 4;

    for (int r = 0; r <= 512; ++r) {
        // ---- barrier: wait all 128 flags >= r ----
        u32 tgt = (u32)r;
        while (true) {
            u32 v0 = __hip_atomic_load(&flags[lane], __ATOMIC_RELAXED,
                                       __HIP_MEMORY_SCOPE_AGENT);
            u32 v1 = __hip_atomic_load(&flags[64 + lane], __ATOMIC_RELAXED,
                                       __HIP_MEMORY_SCOPE_AGENT);
            if (__all((v0 >= tgt) & (v1 >= tgt))) break;
            __builtin_amdgcn_s_sleep(1);
        }
        __builtin_amdgcn_sched_barrier(0);

        f32x4 aE = {}, aO = {}, xE = {}, xO = {};
        u64 xv = 0;
        if (grp == 0) {
            if (r < 512) xv = *(const u64*)(xp + (size_t)r * 131072);
            asm volatile("" : "+v"(wpx_u));   // defeat LICM of Wx1 stream loads
            const u16* wpx = (const u16*)(uintptr_t)wpx_u;
            const u16* h0p = hseq0 + (size_t)r * 32768 + boff;
#pragma unroll
            for (int c = 0; c < 4; ++c) {
                u64 lo8[8], hi8[8];
                s16x8 bx[8];
#pragma unroll
                for (int j = 0; j < 8; ++j) {
                    int q = c * 8 + j;
                    lo8[j] = __hip_atomic_load((const u64*)(h0p + (q * 4 + kq) * 256),
                                               __ATOMIC_RELAXED, __HIP_MEMORY_SCOPE_AGENT);
                    hi8[j] = __hip_atomic_load((const u64*)(h0p + (q * 4 + kq + 2) * 256),
                                               __ATOMIC_RELAXED, __HIP_MEMORY_SCOPE_AGENT);
                    bx[j] = mk8(*(const s16x4*)(wpx + q * 32),
                                *(const s16x4*)(wpx + q * 32 + 16));
                }
#pragma unroll
                for (int j = 0; j < 8; ++j) {
                    int q = c * 8 + j;
                    s16x8 a = mk8(__builtin_bit_cast(s16x4, lo8[j]),
                                  __builtin_bit_cast(s16x4, hi8[j]));
                    if (q & 1) { aO = mfma16(a, bstat[q], aO); xO = mfma16(a, bx[j], xO); }
                    else       { aE = mfma16(a, bstat[q], aE); xE = mfma16(a, bx[j], xE); }
                }
            }
        } else {
            if (r > 0) {
                const u16* h1p = hseq1 + (size_t)(r - 1) * 32768 + boff;
#pragma unroll
                for (int c = 0; c < 4; ++c) {
                    u64 lo8[8], hi8[8];
#pragma unroll
                    for (int j = 0; j < 8; ++j) {
                        int q = c * 8 + j;
                        lo8[j] = __hip_atomic_load((const u64*)(h1p + (q * 4 + kq) * 256),
                                                   __ATOMIC_RELAXED, __HIP_MEMORY_SCOPE_AGENT);
                        hi8[j] = __hip_atomic_load((const u64*)(h1p + (q * 4 + kq + 2) * 256),
                                                   __ATOMIC_RELAXED, __HIP_MEMORY_SCOPE_AGENT);
                    }
#pragma unroll
                    for (int j = 0; j < 8; ++j) {
                        int q = c * 8 + j;
                        s16x8 a = mk8(__builtin_bit_cast(s16x4, lo8[j]),
                                      __builtin_bit_cast(s16x4, hi8[j]));
                        if (q & 1) aO = mfma16(a, bstat[q], aO);
                        else       aE = mfma16(a, bstat[q], aE);
                    }
                }
            }
            *(f32x4*)(&part[wl][lane][0]) = aE + aO;
        }
        __syncthreads();   // publishes B's LDS partial; A's loads/MFMAs done

        if (grp == 0) {
            // ---- L0 epilogue ----
            if (r < 512) {
                f32x4 acc = aE + aO;
                float r0 = acc[0], r1 = acc[1], r2 = acc[2], r3 = acc[3];
                float x0 = __shfl_xor(r0, 1), x1 = __shfl_xor(r1, 1);
                float x2 = __shfl_xor(r2, 1), x3 = __shfl_xor(r3, 1);
                bool o1 = lane & 1;
                float s0 = o1 ? x1 : r0, s1 = o1 ? r1 : x0;
                float s2 = o1 ? x3 : r2, s3 = o1 ? r3 : x2;
                float y0 = __shfl_xor(s0, 2), y1 = __shfl_xor(s1, 2);
                float y2 = __shfl_xor(s2, 2), y3 = __shfl_xor(s3, 2);
                bool o2 = lane & 2;
                float gi = (o2 ? y2 : s0) + h2f((u16)(xv));
                float gf = (o2 ? y3 : s1) + h2f((u16)(xv >> 16));
                float gg = (o2 ? s2 : y0) + h2f((u16)(xv >> 32));
                float go = (o2 ? s3 : y1) + h2f((u16)(xv >> 48));
                float I  = fast_sigmoid(gi);
                float Fg = fast_sigmoid(gf);
                float G  = fast_tanh(gg);
                float O  = fast_sigmoid(go);
                c0 = Fg * c0 + I * G;
                u32 hq = (u32)f2bf(O * fast_tanh(c0));
                u32 o4 = (u32)__shfl_xor((int)hq, 4);
                u32 m32 = (lane & 4) ? ((o4 & 0xffffu) | (hq << 16))
                                     : ((hq & 0xffffu) | (o4 << 16));
                u32 o8 = (u32)__shfl_xor((int)m32, 8);
                u64 m64 = (lane & 8) ? (((u64)o8) | ((u64)m32 << 32))
                                     : (((u64)m32) | ((u64)o8 << 32));
                if ((lane & 12) == 0)
                    __hip_atomic_store((u64*)(hseq0 + (size_t)(r + 1) * 32768 + soff),
                                       m64, __ATOMIC_RELAXED, __HIP_MEMORY_SCOPE_AGENT);
            }
            // ---- L1 epilogue (x-part + B's recurrent partial) ----
            if (r > 0) {
                f32x4 acc = xE + xO + *(const f32x4*)(&part[wl][lane][0]);
                float r0 = acc[0], r1 = acc[1], r2 = acc[2], r3 = acc[3];
                float x0 = __shfl_xor(r0, 1), x1 = __shfl_xor(r1, 1);
                float x2 = __shfl_xor(r2, 1), x3 = __shfl_xor(r3, 1);
                bool o1 = lane & 1;
                float s0 = o1 ? x1 : r0, s1 = o1 ? r1 : x0;
                float s2 = o1 ? x3 : r2, s3 = o1 ? r3 : x2;
                float y0 = __shfl_xor(s0, 2), y1 = __shfl_xor(s1, 2);
                float y2 = __shfl_xor(s2, 2), y3 = __shfl_xor(s3, 2);
                bool o2 = lane & 2;
                float gi = (o2 ? y2 : s0) + b1r[0];
                float gf = (o2 ? y3 : s1) + b1r[1];
                float gg = (o2 ? s2 : y0) + b1r[2];
                float go = (o2 ? s3 : y1) + b1r[3];
                float I  = fast_sigmoid(gi);
                float Fg = fast_sigmoid(gf);
                float G  = fast_tanh(gg);
                float O  = fast_sigmoid(go);
                c1 = Fg * c1 + I * G;
                u32 hq = (u32)f2bf(O * fast_tanh(c1));
                u32 o4 = (u32)__shfl_xor((int)hq, 4);
                u32 m32 = (lane & 4) ? ((o4 & 0xffffu) | (hq << 16))
                                     : ((hq & 0xffffu) | (o4 << 16));
                u32 o8 = (u32)__shfl_xor((int)m32, 8);
                u64 m64 = (lane & 8) ? (((u64)o8) | ((u64)m32 << 32))
                                     : (((u64)m32) | ((u64)o8 << 32));
                if ((lane & 12) == 0)
                    __hip_atomic_store((u64*)(hseq1 + (size_t)r * 32768 + soff),
                                       m64, __ATOMIC_RELAXED, __HIP_MEMORY_SCOPE_AGENT);
            }
        }
        __syncthreads();   // drains group A's sc1 stores (vmcnt) before flag post
        if (tid == 0)
            __hip_atomic_store(&flags[blk], (u32)(r + 1), __ATOMIC_RELAXED,
                               __HIP_MEMORY_SCOPE_AGENT);
    }
}

extern "C" void kernel_launch(void* const* d_in, const int* in_sizes, int n_in,
                              void* d_out, int out_size, void* d_ws, size_t ws_size,
                              hipStream_t stream) {
    const float* x   = (const float*)d_in[0];
    const float* Wx  = (const float*)d_in[1];
    const float* Wh  = (const float*)d_in[2];
    const float* b   = (const float*)d_in[3];
    const float* Wmu = (const float*)d_in[4];
    const float* bmu = (const float*)d_in[5];
    const float* Wls = (const float*)d_in[6];
    const float* bls = (const float*)d_in[7];
    const float* ym  = (const float*)d_in[8];
    float* out = (float*)d_out;

    // workspace (236,061,184 B):
    // [0)            hseq0 [513][32768] u16 = 33,619,968  (aliases xbf 32 MiB)
    // [33,619,968)   hseq1 33,619,968
    // [67,239,936)   wxT   16,777,216   [2][4096][1024]
    // [84,017,152)   whT   16,777,216
    // [100,794,368)  whdT   1,048,576   [512][1024]
    // [101,842,944)  xproj 134,217,728  fp16 gate-interleaved [T*32+b][4096]
    // [236,060,672)  flags 512
    char* ws = (char*)d_ws;
    u16* hseq0 = (u16*)(ws);
    u16* xbf   = (u16*)(ws);
    u16* hseq1 = (u16*)(ws + 33619968);
    u16* wxT   = (u16*)(ws + 67239936);
    u16* whT   = (u16*)(ws + 84017152);
    u16* whdT  = (u16*)(ws + 100794368);
    u16* xproj = (u16*)(ws + 101842944);
    u32* flags = (u32*)(ws + 236060672);

    // prep
    k_f2bf<<<16384, 256, 0, stream>>>(x, xbf, 16777216);
    dim3 tg(128, 32);
    k_transpose_bf<<<tg, 256, 0, stream>>>(Wx,           wxT,           1024, 4096);
    k_transpose_bf<<<tg, 256, 0, stream>>>(Wx + 4194304, wxT + 4194304, 1024, 4096);
    k_transpose_bf<<<tg, 256, 0, stream>>>(Wh,           whT,           1024, 4096);
    k_transpose_bf<<<tg, 256, 0, stream>>>(Wh + 4194304, whT + 4194304, 1024, 4096);
    dim3 hg(8, 32);
    k_transpose_bf<<<hg, 256, 0, stream>>>(Wmu, whdT,          1024, 256);
    k_transpose_bf<<<hg, 256, 0, stream>>>(Wls, whdT + 262144, 1024, 256);

    // layer-0 x-projection (reads xbf, writes xproj)
    k_gemm<0><<<4096, 256, 0, stream>>>(xbf, wxT, b, xproj, nullptr, nullptr, nullptr, 32);

    // zero initial h slots + flags (xbf dead now; hseq0 aliases it)
    hipMemsetAsync(hseq0, 0, 65536, stream);
    hipMemsetAsync(hseq1, 0, 65536, stream);
    hipMemsetAsync(flags, 0, 512, stream);

    // fused 2-layer recurrence (8 waves: group A = L0 + L1-x + epilogues, group B = L1-h)
    k_fused<<<128, 512, 0, stream>>>(whT, wxT + 4194304, whT + 4194304, xproj,
                                     b + 4096, hseq0, hseq1, flags);

    // heads (mu || log_sigma) from hseq1 slots 1..512
    k_gemm<1><<<512, 256, 0, stream>>>(hseq1 + 32768, whdT, bmu, nullptr, out,
                                       bls, ym, 4);
}

// Round 6
// 8023.281 us; speedup vs baseline: 1.5087x; 1.0171x over previous
//
#include <hip/hip_runtime.h>

typedef unsigned short u16;
typedef unsigned int   u32;
typedef unsigned long long u64;
typedef short s16x4 __attribute__((ext_vector_type(4)));
typedef short s16x8 __attribute__((ext_vector_type(8)));
typedef float f32x4 __attribute__((ext_vector_type(4)));
typedef u32   u32x4 __attribute__((ext_vector_type(4)));

#define GK 1024

__device__ inline u16 f2bf(float f) {
    u32 u = __builtin_bit_cast(u32, f);
    u += 0x7FFFu + ((u >> 16) & 1u);
    return (u16)(u >> 16);
}
__device__ inline u16 f2h(float f) {
    _Float16 h = (_Float16)f;
    return __builtin_bit_cast(u16, h);
}
__device__ inline float h2f(u16 u) {
    return (float)__builtin_bit_cast(_Float16, u);
}
__device__ inline float fast_sigmoid(float x) {
    return __builtin_amdgcn_rcpf(1.f + __expf(-x));
}
__device__ inline float fast_tanh(float x) {
    return 1.f - 2.f * __builtin_amdgcn_rcpf(1.f + __expf(2.f * x));
}
__device__ inline f32x4 mfma16(s16x8 a, s16x8 b, f32x4 c) {
    return __builtin_amdgcn_mfma_f32_16x16x32_bf16(a, b, c, 0, 0, 0);
}
__device__ inline s16x8 mk8(s16x4 lo, s16x4 hi) {
    return __builtin_shufflevector(lo, hi, 0, 1, 2, 3, 4, 5, 6, 7);
}

// ---------------- f32 -> bf16 convert (x) ----------------
__global__ void k_f2bf(const float* __restrict__ in, u16* __restrict__ out, int n) {
    int i = (blockIdx.x * 256 + threadIdx.x) * 4;
    if (i < n) {
        float4 v = *(const float4*)(in + i);
        ushort4 o;
        o.x = f2bf(v.x); o.y = f2bf(v.y); o.z = f2bf(v.z); o.w = f2bf(v.w);
        *(ushort4*)(out + i) = o;
    }
}

// ---------------- transpose + convert: out[c][r] = bf16(in[r][c]) ----------------
__global__ void k_transpose_bf(const float* __restrict__ in, u16* __restrict__ out,
                               int R, int C) {
    __shared__ float tile[32][33];
    int tid = threadIdx.x;
    int xs = (tid & 7) * 4;
    int y  = tid >> 3;
    int r0 = blockIdx.y * 32, c0 = blockIdx.x * 32;
    float4 v = *(const float4*)(in + (size_t)(r0 + y) * C + c0 + xs);
    tile[y][xs + 0] = v.x; tile[y][xs + 1] = v.y;
    tile[y][xs + 2] = v.z; tile[y][xs + 3] = v.w;
    __syncthreads();
    ushort4 o;
    o.x = f2bf(tile[xs + 0][y]); o.y = f2bf(tile[xs + 1][y]);
    o.z = f2bf(tile[xs + 2][y]); o.w = f2bf(tile[xs + 3][y]);
    *(ushort4*)(out + (size_t)(c0 + y) * R + r0 + xs) = o;
}

// ---------------- bf16 GEMM: C[m][n] = sum_k A[m][k] * BT[n][k] (+epilogue) ----------------
// MODE 0: A plain [M][1024]; write fp16 gate-interleaved xproj at orow=(m&511)*32+(m>>9).
// MODE 1: A in hseq layout [t][kb(128)][b(32)][u(8)] (base = slot 1): heads epilogue,
//         orow=(m&31)*512+(m>>5): n<256 softplus+ymin -> mu; n>=256 -> log_sigma.
template<int MODE>
__launch_bounds__(256, 2)
__global__ void k_gemm(const u16* __restrict__ A, const u16* __restrict__ BT,
                       const float* __restrict__ bias,
                       u16* __restrict__ Cb, float* __restrict__ Cf,
                       const float* __restrict__ b2, const float* __restrict__ ymin,
                       int gridN) {
    int bid = blockIdx.x;
    int m0 = (bid / gridN) * 128, n0 = (bid % gridN) * 128;
    __shared__ u16 As[128 * 40];
    __shared__ u16 Bs[128 * 40];
    int tid = threadIdx.x;
    int lane = tid & 63, w = tid >> 6;
    int wr = w >> 1, wc = w & 1;
    int rr = lane & 15, r16 = lane >> 4;
    f32x4 acc[4][4] = {};
    for (int kt = 0; kt < GK / 32; ++kt) {
        int k0 = kt * 32;
#pragma unroll
        for (int it = 0; it < 2; ++it) {
            int idx = it * 256 + tid;
            int row = idx >> 2, ch = idx & 3;
            if (MODE == 0) {
                *(u32x4*)(&As[row * 40 + ch * 8]) =
                    *(const u32x4*)(A + (size_t)(m0 + row) * GK + k0 + ch * 8);
            } else {
                int m = m0 + row;
                size_t aaddr = (size_t)(m >> 5) * 32768 + (size_t)((k0 >> 3) + ch) * 256
                             + (size_t)(m & 31) * 8;
                *(u32x4*)(&As[row * 40 + ch * 8]) = *(const u32x4*)(A + aaddr);
            }
            *(u32x4*)(&Bs[row * 40 + ch * 8]) =
                *(const u32x4*)(BT + (size_t)(n0 + row) * GK + k0 + ch * 8);
        }
        __syncthreads();
        s16x8 af[4], bfr[4];
#pragma unroll
        for (int i = 0; i < 4; ++i) {
            int abase = (wr * 64 + i * 16 + rr) * 40 + r16 * 4;
            af[i] = mk8(*(const s16x4*)(&As[abase]), *(const s16x4*)(&As[abase + 16]));
            int bbase = (wc * 64 + i * 16 + rr) * 40 + r16 * 4;
            bfr[i] = mk8(*(const s16x4*)(&Bs[bbase]), *(const s16x4*)(&Bs[bbase + 16]));
        }
#pragma unroll
        for (int i = 0; i < 4; ++i)
#pragma unroll
            for (int j = 0; j < 4; ++j)
                acc[i][j] = mfma16(af[i], bfr[j], acc[i][j]);
        __syncthreads();
    }
#pragma unroll
    for (int i = 0; i < 4; ++i) {
#pragma unroll
        for (int j = 0; j < 4; ++j) {
#pragma unroll
            for (int r = 0; r < 4; ++r) {
                int m = m0 + wr * 64 + i * 16 + r16 * 4 + r;
                int n = n0 + wc * 64 + j * 16 + rr;
                float v = acc[i][j][r];
                if (MODE == 0) {
                    v += bias[n];
                    int orow = (m & 511) * 32 + (m >> 9);
                    int colx = ((n & 1023) << 2) | (n >> 10);   // gate-interleaved
                    Cb[(size_t)orow * 4096 + colx] = f2h(v);
                } else {
                    int orow = (m & 31) * 512 + (m >> 5);
                    if (n < 256) {
                        v += bias[n];
                        float sp = fmaxf(v, 0.f) + log1pf(expf(-fabsf(v)));
                        Cf[(size_t)orow * 256 + n] = sp + ymin[n];
                    } else {
                        v += b2[n - 256];
                        Cf[4194304 + (size_t)orow * 256 + (n - 256)] = v;
                    }
                }
            }
        }
    }
}

// ---------------- fused 2-layer persistent LSTM, LDS-resident weights ----------------
// 128 blocks x 512 threads (8 waves). Wh0/Wh1 MFMA B-frags preloaded into 128 KB LDS
// (ds_read_b128 per use; cannot spill). Group A = waves 0-3: L0 matmul + L1 x-path
// (Wx1 streamed from L2) + both epilogues/stores. Group B = waves 4-7: L1 recurrent
// matmul -> partial via LDS. Wave-0-only flag polling; 3 barriers/round; 513 rounds.
__launch_bounds__(512, 2)
__global__ void k_fused(const u16* __restrict__ Wh0T, const u16* __restrict__ Wx1T,
                        const u16* __restrict__ Wh1T, const u16* __restrict__ xproj,
                        const float* __restrict__ b1,
                        u16* __restrict__ hseq0, u16* __restrict__ hseq1,
                        u32* __restrict__ flags) {
    __shared__ u16 wlds[2][32][128][8];   // [g][q][col=nt*64+lane][8] bf16 frags, 128 KB
    __shared__ float part[4][64][4];
    int tid = threadIdx.x, blk = blockIdx.x;
    int lane = tid & 63, w = tid >> 6;
    int grp = w >> 2, wl = w & 3;
    int mt = wl >> 1, nt = wl & 1;
    int u0 = blk * 8;
    int rr = lane & 15, r16 = lane >> 4;

    // ---- preload Wh0 (waves 0,1) / Wh1 (waves 4,5) frags into LDS, once ----
    int cg = (rr & 3) * 1024 + u0 + nt * 4 + (rr >> 2);
    if (wl < 2) {
        const u16* wsrc = (grp == 0 ? Wh0T : Wh1T) + (size_t)cg * GK + r16 * 4;
#pragma unroll
        for (int q = 0; q < 32; ++q) {
            s16x8 f = mk8(*(const s16x4*)(wsrc + q * 32),
                          *(const s16x4*)(wsrc + q * 32 + 16));
            *(s16x8*)(&wlds[grp][q][nt * 64 + lane][0]) = f;
        }
    }
    u64 wpx_u = (u64)(uintptr_t)(Wx1T + (size_t)cg * GK + r16 * 4);

    int b_    = mt * 16 + (lane >> 4) * 4 + (lane & 3);
    int u_loc = nt * 4 + ((lane >> 2) & 3);
    int unit  = u0 + u_loc;
    float c0 = 0.f, c1 = 0.f;
    float b1r[4];
#pragma unroll
    for (int g = 0; g < 4; ++g) b1r[g] = b1[g * 1024 + unit];

    const u16* xp = xproj + (size_t)b_ * 4096 + (size_t)unit * 4;
    const int boff = (mt * 16 + rr) * 8 + (r16 & 1) * 4;
    const int kq   = (r16 >> 1);
    const int soff = blk * 256 + b_ * 8 + nt * 4;
    const u16* wq = &wlds[grp][0][nt * 64 + lane][0];   // +q*2048B steps

    __syncthreads();   // wlds ready

    for (int r = 0; r <= 512; ++r) {
        // ---- wave 0 polls all 128 flags >= r; barrier releases the block ----
        if (w == 0) {
            u32 tgt = (u32)r;
            while (true) {
                u32 v0 = __hip_atomic_load(&flags[lane], __ATOMIC_RELAXED,
                                           __HIP_MEMORY_SCOPE_AGENT);
                u32 v1 = __hip_atomic_load(&flags[64 + lane], __ATOMIC_RELAXED,
                                           __HIP_MEMORY_SCOPE_AGENT);
                if (__all((v0 >= tgt) & (v1 >= tgt))) break;
                __builtin_amdgcn_s_sleep(1);
            }
        }
        __syncthreads();

        f32x4 aE = {}, aO = {}, xE = {}, xO = {};
        u64 xv = 0;
        if (grp == 0) {
            if (r < 512) xv = *(const u64*)(xp + (size_t)r * 131072);
            asm volatile("" : "+v"(wpx_u));   // defeat LICM of Wx1 stream loads
            const u16* wpx = (const u16*)(uintptr_t)wpx_u;
            const u16* h0p = hseq0 + (size_t)r * 32768 + boff;
#pragma unroll
            for (int c = 0; c < 4; ++c) {
                u64 lo8[8], hi8[8];
                s16x8 bx[8];
#pragma unroll
                for (int j = 0; j < 8; ++j) {
                    int q = c * 8 + j;
                    lo8[j] = __hip_atomic_load((const u64*)(h0p + (q * 4 + kq) * 256),
                                               __ATOMIC_RELAXED, __HIP_MEMORY_SCOPE_AGENT);
                    hi8[j] = __hip_atomic_load((const u64*)(h0p + (q * 4 + kq + 2) * 256),
                                               __ATOMIC_RELAXED, __HIP_MEMORY_SCOPE_AGENT);
                    bx[j] = mk8(*(const s16x4*)(wpx + q * 32),
                                *(const s16x4*)(wpx + q * 32 + 16));
                }
#pragma unroll
                for (int j = 0; j < 8; ++j) {
                    int q = c * 8 + j;
                    s16x8 a = mk8(__builtin_bit_cast(s16x4, lo8[j]),
                                  __builtin_bit_cast(s16x4, hi8[j]));
                    s16x8 bw = *(const s16x8*)(wq + (size_t)q * 1024);
                    if (q & 1) { aO = mfma16(a, bw, aO); xO = mfma16(a, bx[j], xO); }
                    else       { aE = mfma16(a, bw, aE); xE = mfma16(a, bx[j], xE); }
                }
            }
        } else {
            if (r > 0) {
                const u16* h1p = hseq1 + (size_t)(r - 1) * 32768 + boff;
#pragma unroll
                for (int c = 0; c < 4; ++c) {
                    u64 lo8[8], hi8[8];
#pragma unroll
                    for (int j = 0; j < 8; ++j) {
                        int q = c * 8 + j;
                        lo8[j] = __hip_atomic_load((const u64*)(h1p + (q * 4 + kq) * 256),
                                                   __ATOMIC_RELAXED, __HIP_MEMORY_SCOPE_AGENT);
                        hi8[j] = __hip_atomic_load((const u64*)(h1p + (q * 4 + kq + 2) * 256),
                                                   __ATOMIC_RELAXED, __HIP_MEMORY_SCOPE_AGENT);
                    }
#pragma unroll
                    for (int j = 0; j < 8; ++j) {
                        int q = c * 8 + j;
                        s16x8 a = mk8(__builtin_bit_cast(s16x4, lo8[j]),
                                      __builtin_bit_cast(s16x4, hi8[j]));
                        s16x8 bw = *(const s16x8*)(wq + (size_t)q * 1024);
                        if (q & 1) aO = mfma16(a, bw, aO);
                        else       aE = mfma16(a, bw, aE);
                    }
                }
            }
            *(f32x4*)(&part[wl][lane][0]) = aE + aO;
        }
        __syncthreads();   // publishes B's LDS partial

        if (grp == 0) {
            // ---- L0 epilogue ----
            if (r < 512) {
                f32x4 acc = aE + aO;
                float r0 = acc[0], r1 = acc[1], r2 = acc[2], r3 = acc[3];
                float x0 = __shfl_xor(r0, 1), x1 = __shfl_xor(r1, 1);
                float x2 = __shfl_xor(r2, 1), x3 = __shfl_xor(r3, 1);
                bool o1 = lane & 1;
                float s0 = o1 ? x1 : r0, s1 = o1 ? r1 : x0;
                float s2 = o1 ? x3 : r2, s3 = o1 ? r3 : x2;
                float y0 = __shfl_xor(s0, 2), y1 = __shfl_xor(s1, 2);
                float y2 = __shfl_xor(s2, 2), y3 = __shfl_xor(s3, 2);
                bool o2 = lane & 2;
                float gi = (o2 ? y2 : s0) + h2f((u16)(xv));
                float gf = (o2 ? y3 : s1) + h2f((u16)(xv >> 16));
                float gg = (o2 ? s2 : y0) + h2f((u16)(xv >> 32));
                float go = (o2 ? s3 : y1) + h2f((u16)(xv >> 48));
                float I  = fast_sigmoid(gi);
                float Fg = fast_sigmoid(gf);
                float G  = fast_tanh(gg);
                float O  = fast_sigmoid(go);
                c0 = Fg * c0 + I * G;
                u32 hq = (u32)f2bf(O * fast_tanh(c0));
                u32 o4 = (u32)__shfl_xor((int)hq, 4);
                u32 m32 = (lane & 4) ? ((o4 & 0xffffu) | (hq << 16))
                                     : ((hq & 0xffffu) | (o4 << 16));
                u32 o8 = (u32)__shfl_xor((int)m32, 8);
                u64 m64 = (lane & 8) ? (((u64)o8) | ((u64)m32 << 32))
                                     : (((u64)m32) | ((u64)o8 << 32));
                if ((lane & 12) == 0)
                    __hip_atomic_store((u64*)(hseq0 + (size_t)(r + 1) * 32768 + soff),
                                       m64, __ATOMIC_RELAXED, __HIP_MEMORY_SCOPE_AGENT);
            }
            // ---- L1 epilogue (x-part + B's recurrent partial) ----
            if (r > 0) {
                f32x4 acc = xE + xO + *(const f32x4*)(&part[wl][lane][0]);
                float r0 = acc[0], r1 = acc[1], r2 = acc[2], r3 = acc[3];
                float x0 = __shfl_xor(r0, 1), x1 = __shfl_xor(r1, 1);
                float x2 = __shfl_xor(r2, 1), x3 = __shfl_xor(r3, 1);
                bool o1 = lane & 1;
                float s0 = o1 ? x1 : r0, s1 = o1 ? r1 : x0;
                float s2 = o1 ? x3 : r2, s3 = o1 ? r3 : x2;
                float y0 = __shfl_xor(s0, 2), y1 = __shfl_xor(s1, 2);
                float y2 = __shfl_xor(s2, 2), y3 = __shfl_xor(s3, 2);
                bool o2 = lane & 2;
                float gi = (o2 ? y2 : s0) + b1r[0];
                float gf = (o2 ? y3 : s1) + b1r[1];
                float gg = (o2 ? s2 : y0) + b1r[2];
                float go = (o2 ? s3 : y1) + b1r[3];
                float I  = fast_sigmoid(gi);
                float Fg = fast_sigmoid(gf);
                float G  = fast_tanh(gg);
                float O  = fast_sigmoid(go);
                c1 = Fg * c1 + I * G;
                u32 hq = (u32)f2bf(O * fast_tanh(c1));
                u32 o4 = (u32)__shfl_xor((int)hq, 4);
                u32 m32 = (lane & 4) ? ((o4 & 0xffffu) | (hq << 16))
                                     : ((hq & 0xffffu) | (o4 << 16));
                u32 o8 = (u32)__shfl_xor((int)m32, 8);
                u64 m64 = (lane & 8) ? (((u64)o8) | ((u64)m32 << 32))
                                     : (((u64)m32) | ((u64)o8 << 32));
                if ((lane & 12) == 0)
                    __hip_atomic_store((u64*)(hseq1 + (size_t)r * 32768 + soff),
                                       m64, __ATOMIC_RELAXED, __HIP_MEMORY_SCOPE_AGENT);
            }
        }
        __syncthreads();   // drains group A's sc1 stores (vmcnt) before flag post
        if (tid == 0)
            __hip_atomic_store(&flags[blk], (u32)(r + 1), __ATOMIC_RELAXED,
                               __HIP_MEMORY_SCOPE_AGENT);
    }
}

extern "C" void kernel_launch(void* const* d_in, const int* in_sizes, int n_in,
                              void* d_out, int out_size, void* d_ws, size_t ws_size,
                              hipStream_t stream) {
    const float* x   = (const float*)d_in[0];
    const float* Wx  = (const float*)d_in[1];
    const float* Wh  = (const float*)d_in[2];
    const float* b   = (const float*)d_in[3];
    const float* Wmu = (const float*)d_in[4];
    const float* bmu = (const float*)d_in[5];
    const float* Wls = (const float*)d_in[6];
    const float* bls = (const float*)d_in[7];
    const float* ym  = (const float*)d_in[8];
    float* out = (float*)d_out;

    // workspace (236,061,184 B):
    // [0)            hseq0 [513][32768] u16 = 33,619,968  (aliases xbf 32 MiB)
    // [33,619,968)   hseq1 33,619,968
    // [67,239,936)   wxT   16,777,216   [2][4096][1024]
    // [84,017,152)   whT   16,777,216
    // [100,794,368)  whdT   1,048,576   [512][1024]
    // [101,842,944)  xproj 134,217,728  fp16 gate-interleaved [T*32+b][4096]
    // [236,060,672)  flags 512
    char* ws = (char*)d_ws;
    u16* hseq0 = (u16*)(ws);
    u16* xbf   = (u16*)(ws);
    u16* hseq1 = (u16*)(ws + 33619968);
    u16* wxT   = (u16*)(ws + 67239936);
    u16* whT   = (u16*)(ws + 84017152);
    u16* whdT  = (u16*)(ws + 100794368);
    u16* xproj = (u16*)(ws + 101842944);
    u32* flags = (u32*)(ws + 236060672);

    // prep
    k_f2bf<<<16384, 256, 0, stream>>>(x, xbf, 16777216);
    dim3 tg(128, 32);
    k_transpose_bf<<<tg, 256, 0, stream>>>(Wx,           wxT,           1024, 4096);
    k_transpose_bf<<<tg, 256, 0, stream>>>(Wx + 4194304, wxT + 4194304, 1024, 4096);
    k_transpose_bf<<<tg, 256, 0, stream>>>(Wh,           whT,           1024, 4096);
    k_transpose_bf<<<tg, 256, 0, stream>>>(Wh + 4194304, whT + 4194304, 1024, 4096);
    dim3 hg(8, 32);
    k_transpose_bf<<<hg, 256, 0, stream>>>(Wmu, whdT,          1024, 256);
    k_transpose_bf<<<hg, 256, 0, stream>>>(Wls, whdT + 262144, 1024, 256);

    // layer-0 x-projection (reads xbf, writes xproj)
    k_gemm<0><<<4096, 256, 0, stream>>>(xbf, wxT, b, xproj, nullptr, nullptr, nullptr, 32);

    // zero initial h slots + flags (xbf dead now; hseq0 aliases it)
    hipMemsetAsync(hseq0, 0, 65536, stream);
    hipMemsetAsync(hseq1, 0, 65536, stream);
    hipMemsetAsync(flags, 0, 512, stream);

    // fused 2-layer recurrence (LDS-resident Wh frags; wave-0 polling)
    k_fused<<<128, 512, 0, stream>>>(whT, wxT + 4194304, whT + 4194304, xproj,
                                     b + 4096, hseq0, hseq1, flags);

    // heads (mu || log_sigma) from hseq1 slots 1..512
    k_gemm<1><<<512, 256, 0, stream>>>(hseq1 + 32768, whdT, bmu, nullptr, out,
                                       bls, ym, 4);
}